// Round 6
// baseline (544.551 us; speedup 1.0000x reference)
//
#include <hip/hip_runtime.h>
#include <hip/hip_bf16.h>

typedef _Float16 f16x8 __attribute__((ext_vector_type(8)));
typedef float    f32x4 __attribute__((ext_vector_type(4)));

#define B_SZ 512
#define T_SZ 2048
#define D_SZ 256
#define TCHUNK 16
#define NCHUNK (T_SZ / TCHUNK)   // 128

// ---------- kernel 1: W_eff[e,k] = sum_d Wa[e,d]*Wi[d,k];  b_eff[e] = Wa[e,:]@(bi+bh) + ba[e]
__global__ __launch_bounds__(256) void prep_kernel(
    const float* __restrict__ Wa, const float* __restrict__ Wi,
    const float* __restrict__ bi, const float* __restrict__ bh,
    const float* __restrict__ ba,
    _Float16* __restrict__ Weff, float* __restrict__ beff)
{
    int e = blockIdx.x;      // output row (256)
    int d = threadIdx.x;     // output col (256)
    float a0 = 0.f, a1 = 0.f, a2 = 0.f, a3 = 0.f;
    #pragma unroll 4
    for (int k = 0; k < 256; k += 4) {
        a0 = fmaf(Wa[e*256 + k    ], Wi[(k    )*256 + d], a0);
        a1 = fmaf(Wa[e*256 + k + 1], Wi[(k + 1)*256 + d], a1);
        a2 = fmaf(Wa[e*256 + k + 2], Wi[(k + 2)*256 + d], a2);
        a3 = fmaf(Wa[e*256 + k + 3], Wi[(k + 3)*256 + d], a3);
    }
    Weff[e*256 + d] = (_Float16)((a0 + a1) + (a2 + a3));

    __shared__ float red[4];
    float s = Wa[e*256 + d] * (bi[d] + bh[d]);
    s += __shfl_down(s, 32, 64);
    s += __shfl_down(s, 16, 64);
    s += __shfl_down(s,  8, 64);
    s += __shfl_down(s,  4, 64);
    s += __shfl_down(s,  2, 64);
    s += __shfl_down(s,  1, 64);
    if ((d & 63) == 0) red[d >> 6] = s;
    __syncthreads();
    if (d == 0) beff[e] = ba[e] + ((red[0] + red[1]) + (red[2] + red[3]));
}

// ---------- kernel 2: fused GEMM + sigmoid + sum_t attn*x -> ao (B,256)
// 8 waves x 32 cols, swapped MFMA (S^T). x staged fp32 DIRECTLY into LDS via
// global_load_lds (async DMA, zero staging VALU), QUAD-buffered 4x16KB,
// stage-ahead-2 with counted vmcnt(4) (never drained mid-loop), ONE barrier
// per chunk. fp32->fp16 cvt at fragment-read time. Swizzle: linear LDS dest +
// inverse-XOR'd global source + XOR'd LDS reads (rule #21).
__global__ __launch_bounds__(512, 4) void attn_kernel(
    const float* __restrict__ x,          // (B, T, D)
    const _Float16* __restrict__ Weff,    // (256, 256) row-major [e][k]
    const float* __restrict__ beff,       // (256)
    float* __restrict__ ao)               // (B, 256)
{
    const int b    = blockIdx.x;
    const int tid  = threadIdx.x;          // 0..511
    const int wave = tid >> 6;             // 0..7
    const int lane = tid & 63;
    const int l15  = lane & 15;
    const int lq   = lane >> 4;

    __shared__ float xs[4][TCHUNK * 256];  // 4 x 16 KB fp32
    char* xsbase = reinterpret_cast<char*>(&xs[0][0]);

    // Weff fragments (A-operand): lane holds Weff[e = base + l15][k = ks*32 + lq*8 + i]
    const int col0 = wave*32 + l15;
    const int col1 = col0 + 16;
    f16x8 bfA[8], bfB[8];
    #pragma unroll
    for (int ks = 0; ks < 8; ++ks) {
        bfA[ks] = *reinterpret_cast<const f16x8*>(&Weff[col0*256 + ks*32 + lq*8]);
        bfB[ks] = *reinterpret_cast<const f16x8*>(&Weff[col1*256 + ks*32 + lq*8]);
    }
    // bias per accumulator slot: e = wave*32 (+16) + lq*4 + r
    const f32x4 bcA = *reinterpret_cast<const f32x4*>(&beff[wave*32 + lq*4]);
    const f32x4 bcB = *reinterpret_cast<const f32x4*>(&beff[wave*32 + 16 + lq*4]);

    const float* xb = x + (size_t)b * T_SZ * D_SZ;

    // each wave stages rows 2w, 2w+1 of the 16-row chunk (1 row = 1 KB = 1 instr).
    // LDS dest linear; global source pre-XOR'd so XOR'd reads see original data.
    #define STAGE(c)                                                               \
        {                                                                          \
            const int ch = (c);                                                    \
            char* db = xsbase + (ch & 3) * 16384;                                  \
            _Pragma("unroll")                                                      \
            for (int i = 0; i < 2; ++i) {                                          \
                int rw = wave*2 + i;                                               \
                const char* sp = (const char*)(xb + ((size_t)ch*TCHUNK + rw)*256)  \
                                 + ((lane*16) ^ ((rw & 7) << 4));                  \
                __builtin_amdgcn_global_load_lds(                                  \
                    (const __attribute__((address_space(1))) void*)sp,             \
                    (__attribute__((address_space(3))) void*)(db + rw*1024),       \
                    16, 0, 0);                                                     \
            }                                                                      \
        }

    #define COMPUTE(BI)                                                           \
        {                                                                          \
            const char* bp = xsbase + (BI) * 16384;                                \
            const int swz  = (l15 & 7) << 4;                                       \
            const int base = l15 * 1024;                                           \
            f32x4 acc0 = {0.f, 0.f, 0.f, 0.f};                                     \
            f32x4 acc1 = {0.f, 0.f, 0.f, 0.f};                                     \
            _Pragma("unroll")                                                      \
            for (int ks = 0; ks < 8; ++ks) {                                       \
                int cb = ks*128 + lq*32;                                           \
                f32x4 lo = *reinterpret_cast<const f32x4*>(bp + base + ((cb     ) ^ swz)); \
                f32x4 hi = *reinterpret_cast<const f32x4*>(bp + base + ((cb + 16) ^ swz)); \
                f16x8 a;                                                           \
                a[0] = (_Float16)lo[0]; a[1] = (_Float16)lo[1];                    \
                a[2] = (_Float16)lo[2]; a[3] = (_Float16)lo[3];                    \
                a[4] = (_Float16)hi[0]; a[5] = (_Float16)hi[1];                    \
                a[6] = (_Float16)hi[2]; a[7] = (_Float16)hi[3];                    \
                acc0 = __builtin_amdgcn_mfma_f32_16x16x32_f16(bfA[ks], a, acc0, 0, 0, 0); \
                acc1 = __builtin_amdgcn_mfma_f32_16x16x32_f16(bfB[ks], a, acc1, 0, 0, 0); \
            }                                                                      \
            /* epilogue: lane has t = l15, e = wave*32 (+16) + lq*4 + r (fp32!) */ \
            f32x4 xq0 = *reinterpret_cast<const f32x4*>(                           \
                bp + base + ((wave*128      + lq*16) ^ swz));                      \
            f32x4 xq1 = *reinterpret_cast<const f32x4*>(                           \
                bp + base + ((wave*128 + 64 + lq*16) ^ swz));                      \
            _Pragma("unroll")                                                      \
            for (int r = 0; r < 4; ++r) {                                          \
                {                                                                  \
                    float s = acc0[r] + bcA[r];                                    \
                    float attn = __builtin_amdgcn_rcpf(1.f + __expf(-s));          \
                    ao0[r] = fmaf(attn, xq0[r], ao0[r]);                           \
                }                                                                  \
                {                                                                  \
                    float s = acc1[r] + bcB[r];                                    \
                    float attn = __builtin_amdgcn_rcpf(1.f + __expf(-s));          \
                    ao1[r] = fmaf(attn, xq1[r], ao1[r]);                           \
                }                                                                  \
            }                                                                      \
        }

    f32x4 ao0 = {0.f, 0.f, 0.f, 0.f};
    f32x4 ao1 = {0.f, 0.f, 0.f, 0.f};

    STAGE(0);
    STAGE(1);

    #pragma unroll 4
    for (int c = 0; c < NCHUNK; ++c) {
        if (c + 2 < NCHUNK) {
            STAGE(c + 2);                                      // async, stays in flight
            asm volatile("s_waitcnt vmcnt(4)" ::: "memory");   // my stage-c loads landed
        } else if (c + 1 < NCHUNK) {
            asm volatile("s_waitcnt vmcnt(2)" ::: "memory");
        } else {
            asm volatile("s_waitcnt vmcnt(0)" ::: "memory");
        }
        asm volatile("s_waitcnt lgkmcnt(0)" ::: "memory");     // my prior ds_reads done
        __builtin_amdgcn_sched_barrier(0);
        __builtin_amdgcn_s_barrier();                          // everyone's stage-c visible;
                                                               // releases buf[(c+2)&3] overwrite
        COMPUTE(c & 3);
    }

    // sum over t: reduce across l15 within each lq group
    #pragma unroll
    for (int m = 1; m <= 8; m <<= 1) {
        #pragma unroll
        for (int r = 0; r < 4; ++r) {
            ao0[r] += __shfl_xor(ao0[r], m, 64);
            ao1[r] += __shfl_xor(ao1[r], m, 64);
        }
    }
    if (l15 == 0) {
        *reinterpret_cast<f32x4*>(&ao[b*256 + wave*32 +      lq*4]) = ao0;
        *reinterpret_cast<f32x4*>(&ao[b*256 + wave*32 + 16 + lq*4]) = ao1;
    }

    #undef STAGE
    #undef COMPUTE
}

// ---------- kernel 3: LSTM cell (h0=c0=0 => f gate dead, W_hh dead)
// 128 blocks x 4 batches: W_ih rows loaded once per block, reused across 4 batches.
__global__ __launch_bounds__(256) void lstm_kernel(
    const float* __restrict__ ao,        // (B, 256)
    const float* __restrict__ Wih,       // (1024, 256)
    const float* __restrict__ bih,       // (1024)
    const float* __restrict__ bhh,       // (1024)
    float* __restrict__ out)             // h (B*256) | h (B*256) | c (B*256)
{
    const int b0 = blockIdx.x * 4;   // 128 blocks
    const int j  = threadIdx.x;      // 256
    __shared__ float a[4][256];
    #pragma unroll
    for (int bb = 0; bb < 4; ++bb) a[bb][j] = ao[(b0 + bb)*256 + j];
    __syncthreads();

    const float bi_ = bih[j]       + bhh[j];
    const float bg_ = bih[512 + j] + bhh[512 + j];
    const float bo_ = bih[768 + j] + bhh[768 + j];
    float gi[4], gg[4], go[4];
    #pragma unroll
    for (int bb = 0; bb < 4; ++bb) { gi[bb] = bi_; gg[bb] = bg_; go[bb] = bo_; }

    const float* wi = Wih + (size_t)j * 256;
    const float* wg = Wih + (size_t)(512 + j) * 256;
    const float* wo = Wih + (size_t)(768 + j) * 256;
    #pragma unroll 2
    for (int k = 0; k < 256; k += 4) {
        f32x4 w1 = *reinterpret_cast<const f32x4*>(wi + k);
        f32x4 w2 = *reinterpret_cast<const f32x4*>(wg + k);
        f32x4 w3 = *reinterpret_cast<const f32x4*>(wo + k);
        f32x4 av0 = *reinterpret_cast<const f32x4*>(&a[0][k]);
        f32x4 av1 = *reinterpret_cast<const f32x4*>(&a[1][k]);
        f32x4 av2 = *reinterpret_cast<const f32x4*>(&a[2][k]);
        f32x4 av3 = *reinterpret_cast<const f32x4*>(&a[3][k]);
        #pragma unroll
        for (int q = 0; q < 4; ++q) {
            gi[0] = fmaf(w1[q], av0[q], gi[0]); gg[0] = fmaf(w2[q], av0[q], gg[0]); go[0] = fmaf(w3[q], av0[q], go[0]);
            gi[1] = fmaf(w1[q], av1[q], gi[1]); gg[1] = fmaf(w2[q], av1[q], gg[1]); go[1] = fmaf(w3[q], av1[q], go[1]);
            gi[2] = fmaf(w1[q], av2[q], gi[2]); gg[2] = fmaf(w2[q], av2[q], gg[2]); go[2] = fmaf(w3[q], av2[q], go[2]);
            gi[3] = fmaf(w1[q], av3[q], gi[3]); gg[3] = fmaf(w2[q], av3[q], gg[3]); go[3] = fmaf(w3[q], av3[q], go[3]);
        }
    }

    #pragma unroll
    for (int bb = 0; bb < 4; ++bb) {
        float ig = 1.f / (1.f + __expf(-gi[bb]));
        float g  = tanhf(gg[bb]);
        float og = 1.f / (1.f + __expf(-go[bb]));
        float cc = ig * g;
        float hh = og * tanhf(cc);
        out[          (b0 + bb)*256 + j] = hh;
        out[131072 +  (b0 + bb)*256 + j] = hh;
        out[262144 +  (b0 + bb)*256 + j] = cc;
    }
}

extern "C" void kernel_launch(void* const* d_in, const int* in_sizes, int n_in,
                              void* d_out, int out_size, void* d_ws, size_t ws_size,
                              hipStream_t stream) {
    const float* x    = (const float*)d_in[0];
    const float* Wi   = (const float*)d_in[1];
    const float* bi   = (const float*)d_in[2];
    // d_in[3] = Wh (dead: h0 = 0)
    const float* bh   = (const float*)d_in[4];
    const float* Wa   = (const float*)d_in[5];
    const float* ba   = (const float*)d_in[6];
    const float* W_ih = (const float*)d_in[7];
    const float* b_ih = (const float*)d_in[8];
    // d_in[9] = W_hh (dead: h0 = 0)
    const float* b_hh = (const float*)d_in[10];

    char* ws = (char*)d_ws;
    _Float16* Weff = (_Float16*)ws;                  // 128 KB
    float*    beff = (float*)(ws + 128*1024);        // 1 KB
    float*    ao   = (float*)(ws + 132*1024);        // 512 KB

    prep_kernel<<<256, 256, 0, stream>>>(Wa, Wi, bi, bh, ba, Weff, beff);
    attn_kernel<<<B_SZ, 512, 0, stream>>>(x, Weff, beff, ao);
    lstm_kernel<<<128, 256, 0, stream>>>(ao, W_ih, b_ih, b_hh, (float*)d_out);
}

// Round 7
// 350.122 us; speedup vs baseline: 1.5553x; 1.5553x over previous
//
#include <hip/hip_runtime.h>
#include <hip/hip_bf16.h>

typedef _Float16 f16x8 __attribute__((ext_vector_type(8)));
typedef _Float16 f16x4 __attribute__((ext_vector_type(4)));
typedef float    f32x4 __attribute__((ext_vector_type(4)));

#define B_SZ 512
#define T_SZ 2048
#define D_SZ 256
#define TCHUNK 128
#define NCHUNK (T_SZ / TCHUNK)   // 16

// ---------- kernel 1: W_eff[e,k] = sum_d Wa[e,d]*Wi[d,k];  b_eff[e] = Wa[e,:]@(bi+bh) + ba[e]
__global__ __launch_bounds__(256) void prep_kernel(
    const float* __restrict__ Wa, const float* __restrict__ Wi,
    const float* __restrict__ bi, const float* __restrict__ bh,
    const float* __restrict__ ba,
    _Float16* __restrict__ Weff, float* __restrict__ beff)
{
    int e = blockIdx.x;      // output row (256)
    int d = threadIdx.x;     // output col (256)
    float a0 = 0.f, a1 = 0.f, a2 = 0.f, a3 = 0.f;
    #pragma unroll 4
    for (int k = 0; k < 256; k += 4) {
        a0 = fmaf(Wa[e*256 + k    ], Wi[(k    )*256 + d], a0);
        a1 = fmaf(Wa[e*256 + k + 1], Wi[(k + 1)*256 + d], a1);
        a2 = fmaf(Wa[e*256 + k + 2], Wi[(k + 2)*256 + d], a2);
        a3 = fmaf(Wa[e*256 + k + 3], Wi[(k + 3)*256 + d], a3);
    }
    Weff[e*256 + d] = (_Float16)((a0 + a1) + (a2 + a3));

    __shared__ float red[4];
    float s = Wa[e*256 + d] * (bi[d] + bh[d]);
    s += __shfl_down(s, 32, 64);
    s += __shfl_down(s, 16, 64);
    s += __shfl_down(s,  8, 64);
    s += __shfl_down(s,  4, 64);
    s += __shfl_down(s,  2, 64);
    s += __shfl_down(s,  1, 64);
    if ((d & 63) == 0) red[d >> 6] = s;
    __syncthreads();
    if (d == 0) beff[e] = ba[e] + ((red[0] + red[1]) + (red[2] + red[3]));
}

// ---------- kernel 2: fused GEMM + sigmoid + sum_t attn*x -> ao (B,256)
// Round-4/5 proven fragment/swizzle/epilogue code; geometry change only:
// TCHUNK=128 rows per chunk -> 16 barriers total (8x fewer, convoy amortized),
// double-buffered 2x64KB fp16 LDS (1 block/CU, 8 waves), 64-VGPR landing buffer
// (per-wave in-flight 32KB -> block 128KB: Little's-law saturating), VGPR cap 256
// via __launch_bounds__(512,2) so spills are impossible at ~175 VGPR.
__global__ __launch_bounds__(512, 2) void attn_kernel(
    const float* __restrict__ x,          // (B, T, D)
    const _Float16* __restrict__ Weff,    // (256, 256) row-major [e][k]
    const float* __restrict__ beff,       // (256)
    float* __restrict__ ao)               // (B, 256)
{
    const int b    = blockIdx.x;
    const int tid  = threadIdx.x;          // 0..511
    const int wave = tid >> 6;             // 0..7
    const int lane = tid & 63;
    const int l15  = lane & 15;
    const int lq   = lane >> 4;

    __shared__ _Float16 xs[2][TCHUNK * 256];  // 2 x 64 KB, swizzle: byte ^= (row&7)<<4
    char* xsbase = reinterpret_cast<char*>(&xs[0][0]);

    // Weff fragments (A-operand, swapped MFMA): lane holds Weff[e=base+l15][k=ks*32+lq*8+i]
    const int col0 = wave*32 + l15;
    const int col1 = col0 + 16;
    f16x8 bfA[8], bfB[8];
    #pragma unroll
    for (int ks = 0; ks < 8; ++ks) {
        bfA[ks] = *reinterpret_cast<const f16x8*>(&Weff[col0*256 + ks*32 + lq*8]);
        bfB[ks] = *reinterpret_cast<const f16x8*>(&Weff[col1*256 + ks*32 + lq*8]);
    }
    // bias per accumulator slot: e = wave*32 (+16) + lq*4 + r
    const f32x4 bcA = *reinterpret_cast<const f32x4*>(&beff[wave*32 + lq*4]);
    const f32x4 bcB = *reinterpret_cast<const f32x4*>(&beff[wave*32 + 16 + lq*4]);

    const float* xb = x + (size_t)b * T_SZ * D_SZ;

    // staging: thread covers rows {srow + 16*s, s=0..7}, 8 floats at col (tid&31)*8
    const int srow = tid >> 5;             // 0..15
    const int scg  = tid & 31;
    const float* srcp = xb + (size_t)srow * 256 + scg * 8;
    const int swb = (srow*512 + scg*16) ^ ((srow & 7) << 4);   // (row&7) invariant in s

    f32x4 L[16];   // landing buffer, statically indexed via full unroll

    #define LOADC(c)                                                               \
        {                                                                          \
            const float* p0 = srcp + (size_t)(c) * (TCHUNK * D_SZ);                \
            _Pragma("unroll")                                                      \
            for (int s = 0; s < 8; ++s) {                                          \
                const float* p = p0 + (size_t)s * (16 * 256);                      \
                L[2*s    ] = *reinterpret_cast<const f32x4*>(p);                   \
                L[2*s + 1] = *reinterpret_cast<const f32x4*>(p + 4);               \
            }                                                                      \
        }

    #define WRITE(BUF)                                                             \
        {                                                                          \
            _Pragma("unroll")                                                      \
            for (int s = 0; s < 8; ++s) {                                          \
                f16x8 h;                                                           \
                h[0] = (_Float16)L[2*s][0];   h[1] = (_Float16)L[2*s][1];          \
                h[2] = (_Float16)L[2*s][2];   h[3] = (_Float16)L[2*s][3];          \
                h[4] = (_Float16)L[2*s+1][0]; h[5] = (_Float16)L[2*s+1][1];        \
                h[6] = (_Float16)L[2*s+1][2]; h[7] = (_Float16)L[2*s+1][3];        \
                *reinterpret_cast<f16x8*>((BUF) + swb + s*8192) = h;               \
            }                                                                      \
        }

    // lgkm drain (my LDS ops done) -> barrier; does NOT drain vmcnt
    #define SYNC()                                                                 \
        {                                                                          \
            asm volatile("s_waitcnt lgkmcnt(0)" ::: "memory");                     \
            __builtin_amdgcn_sched_barrier(0);                                     \
            __builtin_amdgcn_s_barrier();                                          \
        }

    #define COMPUTE(BUF)                                                           \
        {                                                                          \
            const int aswz = (l15 & 7) << 4;                                       \
            _Pragma("unroll")                                                      \
            for (int rt = 0; rt < 8; ++rt) {                                       \
                const int abase = (rt*16 + l15) * 512;                             \
                f32x4 acc0 = {0.f, 0.f, 0.f, 0.f};                                 \
                f32x4 acc1 = {0.f, 0.f, 0.f, 0.f};                                 \
                _Pragma("unroll")                                                  \
                for (int ks = 0; ks < 8; ++ks) {                                   \
                    int ab = abase + ((ks*64 + lq*16) ^ aswz);                     \
                    f16x8 a = *reinterpret_cast<const f16x8*>((BUF) + ab);         \
                    acc0 = __builtin_amdgcn_mfma_f32_16x16x32_f16(bfA[ks], a, acc0, 0, 0, 0); \
                    acc1 = __builtin_amdgcn_mfma_f32_16x16x32_f16(bfB[ks], a, acc1, 0, 0, 0); \
                }                                                                  \
                /* epilogue: lane has t = rt*16 + l15, e = wave*32 (+16) + lq*4 + r */ \
                int eb0 = abase + ((wave*64      + lq*8) ^ aswz);                  \
                int eb1 = abase + ((wave*64 + 32 + lq*8) ^ aswz);                  \
                f16x4 xq0 = *reinterpret_cast<const f16x4*>((BUF) + eb0);          \
                f16x4 xq1 = *reinterpret_cast<const f16x4*>((BUF) + eb1);          \
                _Pragma("unroll")                                                  \
                for (int r = 0; r < 4; ++r) {                                      \
                    {                                                              \
                        float s = acc0[r] + bcA[r];                                \
                        float attn = __builtin_amdgcn_rcpf(1.f + __expf(-s));      \
                        ao0[r] = fmaf(attn, (float)xq0[r], ao0[r]);                \
                    }                                                              \
                    {                                                              \
                        float s = acc1[r] + bcB[r];                                \
                        float attn = __builtin_amdgcn_rcpf(1.f + __expf(-s));      \
                        ao1[r] = fmaf(attn, (float)xq1[r], ao1[r]);                \
                    }                                                              \
                }                                                                  \
            }                                                                      \
        }

    f32x4 ao0 = {0.f, 0.f, 0.f, 0.f};
    f32x4 ao1 = {0.f, 0.f, 0.f, 0.f};

    LOADC(0);

    for (int c = 0; c < NCHUNK; ++c) {
        char* bp = xsbase + ((c & 1) << 16);
        WRITE(bp);                       // compiler inserts vmcnt for L regs only
        SYNC();                          // chunk c visible to all waves
        if (c + 1 < NCHUNK) LOADC(c + 1);   // refill landing, in flight across compute
        COMPUTE(bp);
        // no second barrier: next WRITE targets the other buffer; all reads of
        // this buffer are lgkm-drained before the next SYNC's barrier.
    }

    // sum over t: reduce across l15 within each lq group
    #pragma unroll
    for (int m = 1; m <= 8; m <<= 1) {
        #pragma unroll
        for (int r = 0; r < 4; ++r) {
            ao0[r] += __shfl_xor(ao0[r], m, 64);
            ao1[r] += __shfl_xor(ao1[r], m, 64);
        }
    }
    if (l15 == 0) {
        *reinterpret_cast<f32x4*>(&ao[b*256 + wave*32 +      lq*4]) = ao0;
        *reinterpret_cast<f32x4*>(&ao[b*256 + wave*32 + 16 + lq*4]) = ao1;
    }

    #undef LOADC
    #undef WRITE
    #undef SYNC
    #undef COMPUTE
}

// ---------- kernel 3: LSTM cell (h0=c0=0 => f gate dead, W_hh dead)
// 128 blocks x 4 batches: W_ih rows loaded once per block, reused across 4 batches.
__global__ __launch_bounds__(256) void lstm_kernel(
    const float* __restrict__ ao,        // (B, 256)
    const float* __restrict__ Wih,       // (1024, 256)
    const float* __restrict__ bih,       // (1024)
    const float* __restrict__ bhh,       // (1024)
    float* __restrict__ out)             // h (B*256) | h (B*256) | c (B*256)
{
    const int b0 = blockIdx.x * 4;   // 128 blocks
    const int j  = threadIdx.x;      // 256
    __shared__ float a[4][256];
    #pragma unroll
    for (int bb = 0; bb < 4; ++bb) a[bb][j] = ao[(b0 + bb)*256 + j];
    __syncthreads();

    const float bi_ = bih[j]       + bhh[j];
    const float bg_ = bih[512 + j] + bhh[512 + j];
    const float bo_ = bih[768 + j] + bhh[768 + j];
    float gi[4], gg[4], go[4];
    #pragma unroll
    for (int bb = 0; bb < 4; ++bb) { gi[bb] = bi_; gg[bb] = bg_; go[bb] = bo_; }

    const float* wi = Wih + (size_t)j * 256;
    const float* wg = Wih + (size_t)(512 + j) * 256;
    const float* wo = Wih + (size_t)(768 + j) * 256;
    #pragma unroll 2
    for (int k = 0; k < 256; k += 4) {
        f32x4 w1 = *reinterpret_cast<const f32x4*>(wi + k);
        f32x4 w2 = *reinterpret_cast<const f32x4*>(wg + k);
        f32x4 w3 = *reinterpret_cast<const f32x4*>(wo + k);
        f32x4 av0 = *reinterpret_cast<const f32x4*>(&a[0][k]);
        f32x4 av1 = *reinterpret_cast<const f32x4*>(&a[1][k]);
        f32x4 av2 = *reinterpret_cast<const f32x4*>(&a[2][k]);
        f32x4 av3 = *reinterpret_cast<const f32x4*>(&a[3][k]);
        #pragma unroll
        for (int q = 0; q < 4; ++q) {
            gi[0] = fmaf(w1[q], av0[q], gi[0]); gg[0] = fmaf(w2[q], av0[q], gg[0]); go[0] = fmaf(w3[q], av0[q], go[0]);
            gi[1] = fmaf(w1[q], av1[q], gi[1]); gg[1] = fmaf(w2[q], av1[q], gg[1]); go[1] = fmaf(w3[q], av1[q], go[1]);
            gi[2] = fmaf(w1[q], av2[q], gi[2]); gg[2] = fmaf(w2[q], av2[q], gg[2]); go[2] = fmaf(w3[q], av2[q], go[2]);
            gi[3] = fmaf(w1[q], av3[q], gi[3]); gg[3] = fmaf(w2[q], av3[q], gg[3]); go[3] = fmaf(w3[q], av3[q], go[3]);
        }
    }

    #pragma unroll
    for (int bb = 0; bb < 4; ++bb) {
        float ig = 1.f / (1.f + __expf(-gi[bb]));
        float g  = tanhf(gg[bb]);
        float og = 1.f / (1.f + __expf(-go[bb]));
        float cc = ig * g;
        float hh = og * tanhf(cc);
        out[          (b0 + bb)*256 + j] = hh;
        out[131072 +  (b0 + bb)*256 + j] = hh;
        out[262144 +  (b0 + bb)*256 + j] = cc;
    }
}

extern "C" void kernel_launch(void* const* d_in, const int* in_sizes, int n_in,
                              void* d_out, int out_size, void* d_ws, size_t ws_size,
                              hipStream_t stream) {
    const float* x    = (const float*)d_in[0];
    const float* Wi   = (const float*)d_in[1];
    const float* bi   = (const float*)d_in[2];
    // d_in[3] = Wh (dead: h0 = 0)
    const float* bh   = (const float*)d_in[4];
    const float* Wa   = (const float*)d_in[5];
    const float* ba   = (const float*)d_in[6];
    const float* W_ih = (const float*)d_in[7];
    const float* b_ih = (const float*)d_in[8];
    // d_in[9] = W_hh (dead: h0 = 0)
    const float* b_hh = (const float*)d_in[10];

    char* ws = (char*)d_ws;
    _Float16* Weff = (_Float16*)ws;                  // 128 KB
    float*    beff = (float*)(ws + 128*1024);        // 1 KB
    float*    ao   = (float*)(ws + 132*1024);        // 512 KB

    prep_kernel<<<256, 256, 0, stream>>>(Wa, Wi, bi, bh, ba, Weff, beff);
    attn_kernel<<<B_SZ, 512, 0, stream>>>(x, Weff, beff, ao);
    lstm_kernel<<<128, 256, 0, stream>>>(ao, W_ih, b_ih, b_hh, (float*)d_out);
}